// Round 13
// baseline (1021.910 us; speedup 1.0000x reference)
//
#include <hip/hip_runtime.h>
#include <hip/hip_bf16.h>

#define NN 30000
#define DIM 128
#define NT 6
#define NE 480000
#define NSLOT 1024
#define NSEG (NT*3*NSLOT)   // 18432
#define SEGCAP 96
#define NBM ((NN+31)/32)    // 938
#define QCAP 2048
#define HB 2048
#define GRID 1024
#define CASTB 256
#define NTASKB 2124          // 118 chunks x 18 rows
#define NAGG (NSEG/16)       // 1152
#define NTASKA (NAGG+16)     // + xWr tasks

typedef __attribute__((ext_vector_type(8))) short bf16x8;
typedef __attribute__((ext_vector_type(4))) float f32x4;

__device__ __forceinline__ float lrelu(float x){ return x > 0.f ? x : 0.2f*x; }
__device__ __forceinline__ unsigned short f2b(float f){
    unsigned u = __float_as_uint(f);
    u = (u + 0x7FFFu + ((u>>16)&1u)) >> 16;
    return (unsigned short)u;
}
__device__ __forceinline__ float b2f(unsigned short b){
    return __uint_as_float(((unsigned)b)<<16);
}
__device__ __forceinline__ float blo(unsigned p){ return b2f((unsigned short)(p & 0xFFFF)); }
__device__ __forceinline__ float bhi(unsigned p){ return b2f((unsigned short)(p >> 16)); }
__device__ __forceinline__ unsigned hsh(int v){ return ((unsigned)v*2654435761u >> 21) & (HB-1); }

struct SMem {
    union U {
        struct { int hk[HB]; int hv[HB]; unsigned bms[NBM]; } p;   // prep hash
        struct { unsigned bms[NBM]; unsigned q[QCAP]; } b;         // build
        unsigned tile[16][72];                                      // aggemm
    } u;
    int qn;
    int taskS;
};

__device__ __forceinline__ void gbar(int* ctr){
    __syncthreads();
    if (threadIdx.x == 0){
        __threadfence();
        __hip_atomic_fetch_add(ctr, 1, __ATOMIC_RELEASE, __HIP_MEMORY_SCOPE_AGENT);
        while (__hip_atomic_load(ctr, __ATOMIC_ACQUIRE, __HIP_MEMORY_SCOPE_AGENT) < GRID)
            __builtin_amdgcn_s_sleep(4);
        __threadfence();
    }
    __syncthreads();
}

__global__ __launch_bounds__(256, 4) void k_all(
        const float* __restrict__ Wp, const float* __restrict__ Wc,
        const float* __restrict__ Wl, const float* __restrict__ Wr,
        const float* __restrict__ aspv, const float* __restrict__ adpv,
        const float* __restrict__ ascv, const float* __restrict__ adcv,
        const float* __restrict__ bp, const float* __restrict__ bc,
        const float* __restrict__ bl, const float* __restrict__ br,
        const int* __restrict__ s, const float* __restrict__ X,
        const int* __restrict__ EI,
        unsigned* __restrict__ bm, unsigned* __restrict__ hmap,
        int* __restrict__ rep, int* __restrict__ cnt, int* __restrict__ csr,
        float* __restrict__ wa, float* __restrict__ bsum,
        unsigned short* __restrict__ WT4,
        unsigned* __restrict__ Xbf,
        float* __restrict__ asp, float* __restrict__ adp,
        float* __restrict__ asc, float* __restrict__ adc,
        float* __restrict__ aggOut, float* __restrict__ xWr,
        int* __restrict__ bars, float* __restrict__ out){
    __shared__ SMem sm;
    const int bid = blockIdx.x, tid = threadIdx.x;
    const int lane = tid & 63, wib = tid >> 6;

    // ================= phase 0: prep =================
    if (bid < 4){
        const float* W = (bid==0) ? Wp : (bid==1) ? Wc : (bid==2) ? Wl : Wr;
        unsigned short* WT = WT4 + (size_t)bid*DIM*DIM;
        if (bid == 0 && tid < DIM) bsum[tid] = bp[tid] + bc[tid] + bl[tid] + br[tid];
        if (bid < 2 && tid < DIM){
            const float* avs = bid ? ascv : aspv;
            const float* avd = bid ? adcv : adpv;
            float* wab = wa + bid*2*DIM;
            float sv = 0.f, dv = 0.f;
            for (int n = 0; n < DIM; n++){
                float w = W[tid*DIM + n];
                sv += w*avs[n]; dv += w*avd[n];
            }
            wab[tid] = sv; wab[DIM + tid] = dv;
        }
        for (int j = tid; j < DIM*DIM; j += 256){
            int n = j >> 7, k = j & 127;
            WT[n*DIM + k] = f2b(W[k*DIM + n]);
        }
    } else if (bid == 4){
        for (int j = tid; j < HB; j += 256){ sm.u.p.hk[j] = -1; sm.u.p.hv[j] = 1<<30; }
        for (int j = tid; j < NBM; j += 256) sm.u.p.bms[j] = 0u;
        __syncthreads();
        for (int i = tid; i < NSLOT; i += 256){
            int v = s[i];
            unsigned idx = hsh(v);
            while (true){
                int old = atomicCAS(&sm.u.p.hk[idx], -1, v);
                if (old == -1 || old == v){ atomicMin(&sm.u.p.hv[idx], i); break; }
                idx = (idx+1)&(HB-1);
            }
            atomicOr(&sm.u.p.bms[v>>5], 1u << (v&31));
        }
        __syncthreads();
        for (int j = tid; j < NBM; j += 256) bm[j] = sm.u.p.bms[j];
        for (int j = tid; j < HB; j += 256){
            int k = sm.u.p.hk[j];
            hmap[j] = (k < 0) ? 0xFFFFFFFFu : (((unsigned)k << 10) | (unsigned)sm.u.p.hv[j]);
        }
        for (int i = tid; i < NSLOT; i += 256){
            int v = s[i];
            unsigned idx = hsh(v);
            while (sm.u.p.hk[idx] != v) idx = (idx+1)&(HB-1);
            rep[i] = sm.u.p.hv[idx];
        }
    } else if (bid < 13){
        int b = bid - 5;
        int per = (NSEG + 7)/8;
        for (int j = b*per + tid; j < (b+1)*per && j < NSEG; j += 256) cnt[j] = 0;
    }
    gbar(&bars[0]);

    // ================= phase 1: cast (blocks 0..CASTB) + build (rest, task pool) =================
    if (bid < CASTB){
        for (int node = bid*4 + wib; node < NN; node += CASTB*4){
            float2 x = *(const float2*)&X[(size_t)node*DIM + lane*2];
            Xbf[(size_t)node*64 + lane] = (unsigned)f2b(x.x) | ((unsigned)f2b(x.y) << 16);
            float sp = x.x*wa[2*lane]     + x.y*wa[2*lane+1];
            float dp = x.x*wa[128+2*lane] + x.y*wa[128+2*lane+1];
            float sc = x.x*wa[256+2*lane] + x.y*wa[256+2*lane+1];
            float dc = x.x*wa[384+2*lane] + x.y*wa[384+2*lane+1];
            #pragma unroll
            for (int off = 32; off; off >>= 1){
                sp += __shfl_xor(sp, off); dp += __shfl_xor(dp, off);
                sc += __shfl_xor(sc, off); dc += __shfl_xor(dc, off);
            }
            if (lane == 0){ asp[node]=sp; adp[node]=dp; asc[node]=sc; adc[node]=dc; }
        }
    } else {
        for (int j = tid; j < NBM; j += 256) sm.u.b.bms[j] = bm[j];
        __syncthreads();
        const int Q = NE/4;
        const int G = 118*256;
        while (true){
            if (tid == 0){ sm.taskS = atomicAdd(&bars[3], 1); sm.qn = 0; }
            __syncthreads();
            int task = sm.taskS;
            if (task >= NTASKB) break;
            int row = task / 118;
            int bxx = task - row*118;
            const int4* dstp = (const int4*)(EI + (size_t)(2*row+1)*NE);
            const int4* srcp = (const int4*)(EI + (size_t)(2*row)*NE);
            int tg = bxx*256 + tid;
            int4 d[4]; int ix[4]; bool va[4];
            #pragma unroll
            for (int u = 0; u < 4; u++){
                ix[u] = tg + u*G;
                va[u] = ix[u] < Q;
                d[u] = va[u] ? dstp[ix[u]] : make_int4(0,0,0,0);
            }
            unsigned mk[4];
            #pragma unroll
            for (int u = 0; u < 4; u++){
                unsigned m0 = va[u] ? ((sm.u.b.bms[d[u].x>>5] >> (d[u].x&31)) & 1u) : 0u;
                unsigned m1 = va[u] ? ((sm.u.b.bms[d[u].y>>5] >> (d[u].y&31)) & 1u) : 0u;
                unsigned m2 = va[u] ? ((sm.u.b.bms[d[u].z>>5] >> (d[u].z&31)) & 1u) : 0u;
                unsigned m3 = va[u] ? ((sm.u.b.bms[d[u].w>>5] >> (d[u].w&31)) & 1u) : 0u;
                mk[u] = m0 | (m1<<1) | (m2<<2) | (m3<<3);
            }
            int4 sv[4];
            #pragma unroll
            for (int u = 0; u < 4; u++)
                if (mk[u]) sv[u] = srcp[ix[u]];
            #pragma unroll
            for (int u = 0; u < 4; u++){
                #pragma unroll
                for (int c = 0; c < 4; c++){
                    bool p = (mk[u] >> c) & 1u;
                    unsigned long long bal = __ballot(p);
                    if (bal){
                        int cw = __popcll(bal);
                        int qb = 0;
                        if (lane == 0) qb = atomicAdd(&sm.qn, cw);
                        qb = __shfl(qb, 0);
                        if (p){
                            int dv = (c==0)?d[u].x:(c==1)?d[u].y:(c==2)?d[u].z:d[u].w;
                            int so = (c==0)?sv[u].x:(c==1)?sv[u].y:(c==2)?sv[u].z:sv[u].w;
                            int pos = qb + __popcll(bal & ((1ull<<lane)-1ull));
                            if (pos < QCAP) sm.u.b.q[pos] = ((unsigned)dv<<15) | (unsigned)so;
                        }
                    }
                }
            }
            __syncthreads();
            int tot = sm.qn; if (tot > QCAP) tot = QCAP;
            __syncthreads();
            int base = row*NSLOT;
            for (int j = tid; j < tot; j += 256){
                unsigned e = sm.u.b.q[j];
                int dst = (int)(e >> 15);
                int src = (int)(e & 32767u);
                unsigned idx = hsh(dst);
                unsigned he;
                while (((he = hmap[idx]) >> 10) != (unsigned)dst) idx = (idx+1)&(HB-1);
                int sl = (int)(he & 1023u);
                int p = atomicAdd(&cnt[base+sl], 1);
                if (p < SEGCAP) csr[(size_t)(base+sl)*SEGCAP + p] = src;
            }
        }
    }
    gbar(&bars[1]);

    // ================= phase 2: aggemm task pool =================
    while (true){
        if (tid == 0) sm.taskS = atomicAdd(&bars[4], 1);
        __syncthreads();
        int task = sm.taskS;
        if (task >= NTASKA) break;
        if (task >= NAGG){
            int blk = task - NAGG;
            const unsigned short* WT = WT4 + (size_t)3*DIM*DIM;
            int r0 = blk*64 + wib*16;
            int ar = r0 + (lane & 15); if (ar > NSLOT-1) ar = NSLOT-1;
            int g4 = lane >> 4;
            const unsigned short* Arow = (const unsigned short*)(Xbf + (size_t)s[ar]*64);
            bf16x8 Af[4];
            #pragma unroll
            for (int ks = 0; ks < 4; ks++)
                Af[ks] = *(const bf16x8*)&Arow[ks*32 + g4*8];
            int cl = lane & 15;
            #pragma unroll
            for (int ct = 0; ct < 8; ct++){
                f32x4 acc = {0.f,0.f,0.f,0.f};
                int bcol = ct*16 + cl;
                #pragma unroll
                for (int ks = 0; ks < 4; ks++){
                    bf16x8 bF = *(const bf16x8*)&WT[bcol*DIM + ks*32 + g4*8];
                    acc = __builtin_amdgcn_mfma_f32_16x16x32_bf16(Af[ks], bF, acc, 0, 0, 0);
                }
                #pragma unroll
                for (int r = 0; r < 4; r++){
                    int rw = r0 + g4*4 + r;
                    if (rw < NSLOT) xWr[(size_t)rw*DIM + bcol] = acc[r];
                }
            }
            continue;
        }
        int base_gw = task*16;
        int tg = base_gw >> 10;
        int g = tg % 3;
        const float* as = (g==1) ? asc : asp;
        const float* ad = (g==1) ? adc : adp;
        for (int k = 0; k < 4; k++){
            int segi = wib*4 + k;
            int gw = base_gw + segi;
            int slot = gw & (NSLOT-1);
            int n = cnt[gw]; if (n > SEGCAP) n = SEGCAP;
            const int* lst = csr + (size_t)gw*SEGCAP;
            int src0 = (lane < n) ? lst[lane] : 0;
            int src1 = (64+lane < n) ? lst[64+lane] : 0;
            int n0 = n < 64 ? n : 64;
            float w0, w1, wself = 0.f, scale;
            int v = -1;
            if (g == 2){
                w0 = (lane < n) ? 1.f : 0.f;
                w1 = (64+lane < n) ? 1.f : 0.f;
                scale = 1.f / (float)(n > 0 ? n : 1);
            } else {
                v = s[slot];
                float adv = ad[v];
                float eself = lrelu(as[v] + adv);
                float e0 = (lane < n)    ? lrelu(as[src0]+adv) : -3e38f;
                float e1 = (64+lane < n) ? lrelu(as[src1]+adv) : -3e38f;
                float m = fmaxf(eself, fmaxf(e0, e1));
                #pragma unroll
                for (int off = 32; off; off >>= 1) m = fmaxf(m, __shfl_xor(m, off));
                w0 = (lane < n)    ? __expf(e0 - m) : 0.f;
                w1 = (64+lane < n) ? __expf(e1 - m) : 0.f;
                float ds = w0 + w1;
                #pragma unroll
                for (int off = 32; off; off >>= 1) ds += __shfl_xor(ds, off);
                wself = __expf(eself - m);
                scale = 1.f / (wself + ds);
            }
            float a0 = 0.f, a1 = 0.f;
            int j = 0;
            for (; j+7 < n0; j += 8){
                int   si[8]; float qi[8]; unsigned ki[8];
                #pragma unroll
                for (int u = 0; u < 8; u++){ si[u] = __shfl(src0, j+u); qi[u] = __shfl(w0, j+u); }
                #pragma unroll
                for (int u = 0; u < 8; u++) ki[u] = Xbf[(size_t)si[u]*64 + lane];
                #pragma unroll
                for (int u = 0; u < 8; u++){ a0 += qi[u]*blo(ki[u]); a1 += qi[u]*bhi(ki[u]); }
            }
            for (; j+3 < n0; j += 4){
                int s0=__shfl(src0,j), s1=__shfl(src0,j+1), s2=__shfl(src0,j+2), s3=__shfl(src0,j+3);
                float q0=__shfl(w0,j), q1=__shfl(w0,j+1), q2=__shfl(w0,j+2), q3=__shfl(w0,j+3);
                unsigned k0=Xbf[(size_t)s0*64+lane];
                unsigned k1=Xbf[(size_t)s1*64+lane];
                unsigned k2=Xbf[(size_t)s2*64+lane];
                unsigned k3=Xbf[(size_t)s3*64+lane];
                a0 += q0*blo(k0) + q1*blo(k1) + q2*blo(k2) + q3*blo(k3);
                a1 += q0*bhi(k0) + q1*bhi(k1) + q2*bhi(k2) + q3*bhi(k3);
            }
            for (; j < n0; j++){
                int sj=__shfl(src0,j);
                float qj=__shfl(w0,j);
                unsigned pk=Xbf[(size_t)sj*64+lane];
                a0 += qj*blo(pk); a1 += qj*bhi(pk);
            }
            for (j = 64; j < n; j++){
                int sj=__shfl(src1,j-64);
                float qj=__shfl(w1,j-64);
                unsigned pk=Xbf[(size_t)sj*64+lane];
                a0 += qj*blo(pk); a1 += qj*bhi(pk);
            }
            if (g < 2){
                unsigned pk = Xbf[(size_t)v*64 + lane];
                a0 += wself*blo(pk); a1 += wself*bhi(pk);
            }
            sm.u.tile[segi][lane] = (unsigned)f2b(a0*scale) | ((unsigned)f2b(a1*scale) << 16);
        }
        __syncthreads();
        const unsigned short* WT = WT4 + (size_t)g*DIM*DIM;
        int r = lane & 15, g4 = lane >> 4;
        bf16x8 Af[4];
        #pragma unroll
        for (int ks = 0; ks < 4; ks++)
            Af[ks] = *(const bf16x8*)&sm.u.tile[r][ks*16 + g4*4];
        #pragma unroll
        for (int ct = 0; ct < 2; ct++){
            f32x4 acc = {0.f,0.f,0.f,0.f};
            int bcol = wib*32 + ct*16 + r;
            #pragma unroll
            for (int ks = 0; ks < 4; ks++){
                bf16x8 bF = *(const bf16x8*)&WT[bcol*DIM + ks*32 + g4*8];
                acc = __builtin_amdgcn_mfma_f32_16x16x32_bf16(Af[ks], bF, acc, 0, 0, 0);
            }
            #pragma unroll
            for (int rr = 0; rr < 4; rr++){
                int segrow = g4*4 + rr;
                aggOut[(size_t)(base_gw + segrow)*DIM + bcol] = acc[rr];
            }
        }
        __syncthreads();
    }
    gbar(&bars[2]);

    // ================= phase 3: gather =================
    for (int i = bid*256 + tid; i < NT*NSLOT*DIM; i += GRID*256){
        int d = i & 127;
        int r = (i >> 7) & (NSLOT-1);
        int t = i >> 17;
        int rp = rep[r];
        size_t base = ((size_t)(t*3)*NSLOT + rp)*DIM + d;
        out[i] = (aggOut[base] + aggOut[base + NSLOT*DIM] + aggOut[base + 2*NSLOT*DIM]
                  + xWr[(size_t)rp*DIM + d] + bsum[d]) * (1.f/3.f);
    }
}

extern "C" void kernel_launch(void* const* d_in, const int* in_sizes, int n_in,
                              void* d_out, int out_size, void* d_ws, size_t ws_size,
                              hipStream_t stream) {
    const int*   s    = (const int*)d_in[0];
    const int*   EI   = (const int*)d_in[3];
    const float* X    = (const float*)d_in[4];
    const float* Wp   = (const float*)d_in[5];
    const float* aspv = (const float*)d_in[6];
    const float* adpv = (const float*)d_in[7];
    const float* bp   = (const float*)d_in[8];
    const float* Wc   = (const float*)d_in[9];
    const float* ascv = (const float*)d_in[10];
    const float* adcv = (const float*)d_in[11];
    const float* bc   = (const float*)d_in[12];
    const float* Wl   = (const float*)d_in[13];
    const float* bl   = (const float*)d_in[14];
    const float* Wr   = (const float*)d_in[15];
    const float* br   = (const float*)d_in[16];
    float* out = (float*)d_out;

    char* w = (char*)d_ws;
    unsigned* Xbf = (unsigned*)w; w += (size_t)NN*64*4;
    unsigned short* WT4 = (unsigned short*)w; w += (size_t)4*DIM*DIM*2;
    float* wa  = (float*)w; w += (size_t)4*DIM*4;
    float* bsum = (float*)w; w += (size_t)DIM*4;
    float* asp = (float*)w; w += (size_t)NN*4;
    float* adp = (float*)w; w += (size_t)NN*4;
    float* asc = (float*)w; w += (size_t)NN*4;
    float* adc = (float*)w; w += (size_t)NN*4;
    unsigned* bm = (unsigned*)w; w += (size_t)((NBM+3)&~3)*4;
    unsigned* hmap = (unsigned*)w; w += (size_t)HB*4;
    int* rep  = (int*)w; w += (size_t)NSLOT*4;
    int* cnt  = (int*)w; w += (size_t)NSEG*4;
    int* csr  = (int*)w; w += (size_t)NSEG*SEGCAP*4;
    float* aggOut = (float*)w; w += (size_t)NSEG*DIM*4;
    float* xWr = (float*)w; w += (size_t)NSLOT*DIM*4;
    int* bars = (int*)w; w += (size_t)8*4;

    hipMemsetAsync(bars, 0, 8*sizeof(int), stream);
    k_all<<<GRID, 256, 0, stream>>>(Wp, Wc, Wl, Wr, aspv, adpv, ascv, adcv,
                                    bp, bc, bl, br, s, X, EI,
                                    bm, hmap, rep, cnt, csr, wa, bsum, WT4,
                                    Xbf, asp, adp, asc, adc, aggOut, xWr,
                                    bars, out);
}

// Round 15
// 77.414 us; speedup vs baseline: 13.2006x; 13.2006x over previous
//
#include <hip/hip_runtime.h>
#include <hip/hip_bf16.h>

#define NN 30000
#define DIM 128
#define NT 6
#define NE 480000
#define NSLOT 1024
#define NSEG (NT*3*NSLOT)   // 18432
#define SEGCAP 96
#define NBM ((NN+31)/32)    // 938
#define QCAP 2048
#define HB 2048
#define NBUILD 2124         // 118*18
#define NCAST 876
#define NAGG (NSEG/16)      // 1152

typedef __attribute__((ext_vector_type(8))) short bf16x8;
typedef __attribute__((ext_vector_type(4))) float f32x4;
typedef __attribute__((ext_vector_type(4))) int i32x4;
typedef __attribute__((ext_vector_type(2))) float f32x2;

__device__ __forceinline__ float lrelu(float x){ return x > 0.f ? x : 0.2f*x; }
__device__ __forceinline__ unsigned short f2b(float f){
    unsigned u = __float_as_uint(f);
    u = (u + 0x7FFFu + ((u>>16)&1u)) >> 16;
    return (unsigned short)u;
}
__device__ __forceinline__ float b2f(unsigned short b){
    return __uint_as_float(((unsigned)b)<<16);
}
__device__ __forceinline__ float blo(unsigned p){ return b2f((unsigned short)(p & 0xFFFF)); }
__device__ __forceinline__ float bhi(unsigned p){ return b2f((unsigned short)(p >> 16)); }
__device__ __forceinline__ unsigned hsh(int v){ return ((unsigned)v*2654435761u >> 21) & (HB-1); }
__device__ __forceinline__ i32x4 ntld4(const int* p){
    return __builtin_nontemporal_load((const i32x4*)p);
}

// blocks 0..3: WT transpose (+wa for 0,1); block 4: hash/bitmap/rep; blocks 5..12: zero cnt
__global__ void k_prep(const float* __restrict__ Wp, const float* __restrict__ Wc,
        const float* __restrict__ Wl, const float* __restrict__ Wr,
        const float* __restrict__ aspv, const float* __restrict__ adpv,
        const float* __restrict__ ascv, const float* __restrict__ adcv,
        const int* __restrict__ s, unsigned* __restrict__ bm,
        unsigned* __restrict__ hmap, int* __restrict__ rep, int* __restrict__ cnt,
        float* __restrict__ wa, unsigned short* __restrict__ WT4){
    int m = blockIdx.x, t = threadIdx.x;
    if (m >= 5){
        int b = m - 5;
        int per = (NSEG + 7)/8;
        for (int j = b*per + t; j < (b+1)*per && j < NSEG; j += 256) cnt[j] = 0;
        return;
    }
    if (m == 4){
        __shared__ int hk[HB];
        __shared__ int hv[HB];
        __shared__ unsigned bms[NBM];
        for (int j = t; j < HB; j += 256){ hk[j] = -1; hv[j] = 1<<30; }
        for (int j = t; j < NBM; j += 256) bms[j] = 0u;
        __syncthreads();
        for (int i = t; i < NSLOT; i += 256){
            int v = s[i];
            unsigned idx = hsh(v);
            while (true){
                int old = atomicCAS(&hk[idx], -1, v);
                if (old == -1 || old == v){ atomicMin(&hv[idx], i); break; }
                idx = (idx+1)&(HB-1);
            }
            atomicOr(&bms[v>>5], 1u << (v&31));
        }
        __syncthreads();
        for (int j = t; j < NBM; j += 256) bm[j] = bms[j];
        for (int j = t; j < HB; j += 256){
            int k = hk[j];
            hmap[j] = (k < 0) ? 0xFFFFFFFFu : (((unsigned)k << 10) | (unsigned)hv[j]);
        }
        for (int i = t; i < NSLOT; i += 256){
            int v = s[i];
            unsigned idx = hsh(v);
            while (hk[idx] != v) idx = (idx+1)&(HB-1);
            rep[i] = hv[idx];
        }
        return;
    }
    const float* W = (m==0) ? Wp : (m==1) ? Wc : (m==2) ? Wl : Wr;
    unsigned short* WT = WT4 + (size_t)m*DIM*DIM;
    if (m < 2 && t < DIM){
        const float* avs = m ? ascv : aspv;
        const float* avd = m ? adcv : adpv;
        float* wab = wa + m*2*DIM;
        float sv = 0.f, dv = 0.f;
        for (int n = 0; n < DIM; n++){
            float w = W[t*DIM + n];
            sv += w*avs[n]; dv += w*avd[n];
        }
        wab[t] = sv; wab[DIM + t] = dv;
    }
    for (int j = t; j < DIM*DIM; j += blockDim.x){
        int n = j >> 7, k = j & 127;
        WT[n*DIM + k] = f2b(W[k*DIM + n]);
    }
}

// blocks [0,NCAST): cast (grid-stride, wave/node); [NCAST, NCAST+NBUILD): CSR build
__global__ __launch_bounds__(256) void k_castbuild(
        const float* __restrict__ X, const float* __restrict__ wa,
        unsigned* __restrict__ Xbf,
        float* __restrict__ asp, float* __restrict__ adp,
        float* __restrict__ asc, float* __restrict__ adc,
        const int* __restrict__ EI,
        const unsigned* __restrict__ bm, const unsigned* __restrict__ hmap,
        int* __restrict__ cnt, int* __restrict__ csr){
    __shared__ unsigned bms[NBM];
    __shared__ unsigned q[QCAP];
    __shared__ int qn;
    int bx = blockIdx.x;
    int lane = threadIdx.x & 63;
    int wib = threadIdx.x >> 6;
    if (bx < NCAST){
        for (int node = bx*4 + wib; node < NN; node += NCAST*4){
            f32x2 x = __builtin_nontemporal_load(
                (const f32x2*)&X[(size_t)node*DIM + lane*2]);
            Xbf[(size_t)node*64 + lane] = (unsigned)f2b(x.x) | ((unsigned)f2b(x.y) << 16);
            float sp = x.x*wa[2*lane]     + x.y*wa[2*lane+1];
            float dp = x.x*wa[128+2*lane] + x.y*wa[128+2*lane+1];
            float sc = x.x*wa[256+2*lane] + x.y*wa[256+2*lane+1];
            float dc = x.x*wa[384+2*lane] + x.y*wa[384+2*lane+1];
            #pragma unroll
            for (int off = 32; off; off >>= 1){
                sp += __shfl_xor(sp, off); dp += __shfl_xor(dp, off);
                sc += __shfl_xor(sc, off); dc += __shfl_xor(dc, off);
            }
            if (lane == 0){ asp[node]=sp; adp[node]=dp; asc[node]=sc; adc[node]=dc; }
        }
        return;
    }
    int bb = bx - NCAST;
    int row = bb / 118, bxx = bb - row*118;
    for (int j = threadIdx.x; j < NBM; j += 256) bms[j] = bm[j];
    if (threadIdx.x == 0) qn = 0;
    __syncthreads();
    const int Q = NE/4;
    const int G = 118*256;
    const int* dstp = EI + (size_t)(2*row+1)*NE;
    const int* srcp = EI + (size_t)(2*row)*NE;
    int tid = bxx*256 + threadIdx.x;

    i32x4 d[4]; int ix[4]; bool va[4];
    #pragma unroll
    for (int u = 0; u < 4; u++){
        ix[u] = tid + u*G;
        va[u] = ix[u] < Q;
        if (va[u]) d[u] = ntld4(dstp + ix[u]*4);
        else       d[u] = (i32x4){0,0,0,0};
    }
    unsigned mk[4];
    #pragma unroll
    for (int u = 0; u < 4; u++){
        unsigned m0 = va[u] ? ((bms[d[u].x>>5] >> (d[u].x&31)) & 1u) : 0u;
        unsigned m1 = va[u] ? ((bms[d[u].y>>5] >> (d[u].y&31)) & 1u) : 0u;
        unsigned m2 = va[u] ? ((bms[d[u].z>>5] >> (d[u].z&31)) & 1u) : 0u;
        unsigned m3 = va[u] ? ((bms[d[u].w>>5] >> (d[u].w&31)) & 1u) : 0u;
        mk[u] = m0 | (m1<<1) | (m2<<2) | (m3<<3);
    }
    i32x4 sv[4];
    #pragma unroll
    for (int u = 0; u < 4; u++)
        if (mk[u]) sv[u] = ntld4(srcp + ix[u]*4);
    #pragma unroll
    for (int u = 0; u < 4; u++){
        #pragma unroll
        for (int c = 0; c < 4; c++){
            bool p = (mk[u] >> c) & 1u;
            unsigned long long bal = __ballot(p);
            if (bal){
                int cntw = __popcll(bal);
                int base = 0;
                if (lane == 0) base = atomicAdd(&qn, cntw);
                base = __shfl(base, 0);
                if (p){
                    int dv = (c==0)?d[u].x:(c==1)?d[u].y:(c==2)?d[u].z:d[u].w;
                    int so = (c==0)?sv[u].x:(c==1)?sv[u].y:(c==2)?sv[u].z:sv[u].w;
                    int pos = base + __popcll(bal & ((1ull<<lane)-1ull));
                    if (pos < QCAP) q[pos] = ((unsigned)dv<<15) | (unsigned)so;
                }
            }
        }
    }
    __syncthreads();
    int base = row*NSLOT;
    int tot = qn; if (tot > QCAP) tot = QCAP;
    for (int j = threadIdx.x; j < tot; j += 256){
        unsigned e = q[j];
        int dst = (int)(e >> 15);
        int src = (int)(e & 32767u);
        unsigned idx = hsh(dst);
        unsigned he;
        while (((he = hmap[idx]) >> 10) != (unsigned)dst) idx = (idx+1)&(HB-1);
        int sl = (int)(he & 1023u);
        int p = atomicAdd(&cnt[base+sl], 1);
        if (p < SEGCAP) csr[(size_t)(base+sl)*SEGCAP + p] = src;
    }
}

// blocks [0,NAGG): 16 segments/block -> aggregate to LDS -> 16x128x128 MFMA -> aggOut
// blocks [NAGG, NAGG+16): Xbf[s]@WrT -> xWr
__global__ __launch_bounds__(256) void k_aggemm(const unsigned* __restrict__ Xbf,
        const float* __restrict__ asp, const float* __restrict__ adp,
        const float* __restrict__ asc, const float* __restrict__ adc,
        const int* __restrict__ s, const int* __restrict__ cnt, const int* __restrict__ csr,
        const unsigned short* __restrict__ WT4,
        float* __restrict__ aggOut, float* __restrict__ xWr){
    __shared__ unsigned tile[16][72];   // 288B row: 16B-aligned, low-conflict
    int bx = blockIdx.x;
    int lane = threadIdx.x & 63;
    int wib = threadIdx.x >> 6;
    if (bx >= NAGG){
        int blk = bx - NAGG;
        const unsigned short* WT = WT4 + (size_t)3*DIM*DIM;
        int r0 = blk*64 + wib*16;
        int ar = r0 + (lane & 15); if (ar > NSLOT-1) ar = NSLOT-1;
        int g4 = lane >> 4;
        const unsigned short* Arow = (const unsigned short*)(Xbf + (size_t)s[ar]*64);
        bf16x8 Af[4];
        #pragma unroll
        for (int ks = 0; ks < 4; ks++)
            Af[ks] = *(const bf16x8*)&Arow[ks*32 + g4*8];
        int cl = lane & 15;
        #pragma unroll
        for (int ct = 0; ct < 8; ct++){
            f32x4 acc = {0.f,0.f,0.f,0.f};
            int bcol = ct*16 + cl;
            #pragma unroll
            for (int ks = 0; ks < 4; ks++){
                bf16x8 bF = *(const bf16x8*)&WT[bcol*DIM + ks*32 + g4*8];
                acc = __builtin_amdgcn_mfma_f32_16x16x32_bf16(Af[ks], bF, acc, 0, 0, 0);
            }
            #pragma unroll
            for (int r = 0; r < 4; r++){
                int rw = r0 + g4*4 + r;
                if (rw < NSLOT) xWr[(size_t)rw*DIM + bcol] = acc[r];
            }
        }
        return;
    }
    int base_gw = bx*16;
    int tg = base_gw >> 10;
    int g = tg % 3;
    const float* as = (g==1) ? asc : asp;
    const float* ad = (g==1) ? adc : adp;
    // aggregate 4 segments per wave
    for (int k = 0; k < 4; k++){
        int segi = wib*4 + k;
        int gw = base_gw + segi;
        int slot = gw & (NSLOT-1);
        int n = cnt[gw]; if (n > SEGCAP) n = SEGCAP;
        const int* lst = csr + (size_t)gw*SEGCAP;
        int src0 = (lane < n) ? lst[lane] : 0;
        int src1 = (64+lane < n) ? lst[64+lane] : 0;
        int n0 = n < 64 ? n : 64;
        float w0, w1, wself = 0.f, scale;
        int v = -1;
        if (g == 2){
            w0 = (lane < n) ? 1.f : 0.f;
            w1 = (64+lane < n) ? 1.f : 0.f;
            scale = 1.f / (float)(n > 0 ? n : 1);
        } else {
            v = s[slot];
            float adv = ad[v];
            float eself = lrelu(as[v] + adv);
            float e0 = (lane < n)    ? lrelu(as[src0]+adv) : -3e38f;
            float e1 = (64+lane < n) ? lrelu(as[src1]+adv) : -3e38f;
            float m = fmaxf(eself, fmaxf(e0, e1));
            #pragma unroll
            for (int off = 32; off; off >>= 1) m = fmaxf(m, __shfl_xor(m, off));
            w0 = (lane < n)    ? __expf(e0 - m) : 0.f;
            w1 = (64+lane < n) ? __expf(e1 - m) : 0.f;
            float ds = w0 + w1;
            #pragma unroll
            for (int off = 32; off; off >>= 1) ds += __shfl_xor(ds, off);
            wself = __expf(eself - m);
            scale = 1.f / (wself + ds);
        }
        float a0 = 0.f, a1 = 0.f;
        int j = 0;
        for (; j+7 < n0; j += 8){
            int   si[8]; float qi[8]; unsigned ki[8];
            #pragma unroll
            for (int u = 0; u < 8; u++){ si[u] = __shfl(src0, j+u); qi[u] = __shfl(w0, j+u); }
            #pragma unroll
            for (int u = 0; u < 8; u++) ki[u] = Xbf[(size_t)si[u]*64 + lane];
            #pragma unroll
            for (int u = 0; u < 8; u++){ a0 += qi[u]*blo(ki[u]); a1 += qi[u]*bhi(ki[u]); }
        }
        for (; j+3 < n0; j += 4){
            int s0=__shfl(src0,j), s1=__shfl(src0,j+1), s2=__shfl(src0,j+2), s3=__shfl(src0,j+3);
            float q0=__shfl(w0,j), q1=__shfl(w0,j+1), q2=__shfl(w0,j+2), q3=__shfl(w0,j+3);
            unsigned k0=Xbf[(size_t)s0*64+lane];
            unsigned k1=Xbf[(size_t)s1*64+lane];
            unsigned k2=Xbf[(size_t)s2*64+lane];
            unsigned k3=Xbf[(size_t)s3*64+lane];
            a0 += q0*blo(k0) + q1*blo(k1) + q2*blo(k2) + q3*blo(k3);
            a1 += q0*bhi(k0) + q1*bhi(k1) + q2*bhi(k2) + q3*bhi(k3);
        }
        for (; j < n0; j++){
            int sj=__shfl(src0,j);
            float qj=__shfl(w0,j);
            unsigned pk=Xbf[(size_t)sj*64+lane];
            a0 += qj*blo(pk); a1 += qj*bhi(pk);
        }
        for (j = 64; j < n; j++){
            int sj=__shfl(src1,j-64);
            float qj=__shfl(w1,j-64);
            unsigned pk=Xbf[(size_t)sj*64+lane];
            a0 += qj*blo(pk); a1 += qj*bhi(pk);
        }
        if (g < 2){
            unsigned pk = Xbf[(size_t)v*64 + lane];
            a0 += wself*blo(pk); a1 += wself*bhi(pk);
        }
        tile[segi][lane] = (unsigned)f2b(a0*scale) | ((unsigned)f2b(a1*scale) << 16);
    }
    __syncthreads();
    // GEMM: 16 rows x 128 cols, wave wib does cols [wib*32, wib*32+32)
    const unsigned short* WT = WT4 + (size_t)g*DIM*DIM;
    int r = lane & 15, g4 = lane >> 4;
    bf16x8 Af[4];
    #pragma unroll
    for (int ks = 0; ks < 4; ks++)
        Af[ks] = *(const bf16x8*)&tile[r][ks*16 + g4*4];
    #pragma unroll
    for (int ct = 0; ct < 2; ct++){
        f32x4 acc = {0.f,0.f,0.f,0.f};
        int bcol = wib*32 + ct*16 + r;
        #pragma unroll
        for (int ks = 0; ks < 4; ks++){
            bf16x8 bF = *(const bf16x8*)&WT[bcol*DIM + ks*32 + g4*8];
            acc = __builtin_amdgcn_mfma_f32_16x16x32_bf16(Af[ks], bF, acc, 0, 0, 0);
        }
        #pragma unroll
        for (int rr = 0; rr < 4; rr++){
            int segrow = g4*4 + rr;
            aggOut[(size_t)(base_gw + segrow)*DIM + bcol] = acc[rr];
        }
    }
}

__global__ void k_gather(const int* __restrict__ rep,
                         const float* __restrict__ aggOut, const float* __restrict__ xWr,
                         const float* __restrict__ bp, const float* __restrict__ bc,
                         const float* __restrict__ bl, const float* __restrict__ br,
                         float* __restrict__ out){
    int i = blockIdx.x*blockDim.x + threadIdx.x;
    if (i >= NT*NSLOT*DIM) return;
    int d = i & 127;
    int r = (i >> 7) & (NSLOT-1);
    int t = i >> 17;
    int rp = rep[r];
    size_t base = ((size_t)(t*3)*NSLOT + rp)*DIM + d;
    out[i] = (aggOut[base] + aggOut[base + NSLOT*DIM] + aggOut[base + 2*NSLOT*DIM]
              + xWr[(size_t)rp*DIM + d]
              + bp[d] + bc[d] + bl[d] + br[d]) * (1.f/3.f);
}

extern "C" void kernel_launch(void* const* d_in, const int* in_sizes, int n_in,
                              void* d_out, int out_size, void* d_ws, size_t ws_size,
                              hipStream_t stream) {
    const int*   s    = (const int*)d_in[0];
    const int*   EI   = (const int*)d_in[3];
    const float* X    = (const float*)d_in[4];
    const float* Wp   = (const float*)d_in[5];
    const float* aspv = (const float*)d_in[6];
    const float* adpv = (const float*)d_in[7];
    const float* bp   = (const float*)d_in[8];
    const float* Wc   = (const float*)d_in[9];
    const float* ascv = (const float*)d_in[10];
    const float* adcv = (const float*)d_in[11];
    const float* bc   = (const float*)d_in[12];
    const float* Wl   = (const float*)d_in[13];
    const float* bl   = (const float*)d_in[14];
    const float* Wr   = (const float*)d_in[15];
    const float* br   = (const float*)d_in[16];
    float* out = (float*)d_out;

    char* w = (char*)d_ws;
    unsigned* Xbf = (unsigned*)w; w += (size_t)NN*64*4;
    unsigned short* WT4 = (unsigned short*)w; w += (size_t)4*DIM*DIM*2;
    float* wa  = (float*)w; w += (size_t)4*DIM*4;
    float* asp = (float*)w; w += (size_t)NN*4;
    float* adp = (float*)w; w += (size_t)NN*4;
    float* asc = (float*)w; w += (size_t)NN*4;
    float* adc = (float*)w; w += (size_t)NN*4;
    unsigned* bm = (unsigned*)w; w += (size_t)((NBM+3)&~3)*4;
    unsigned* hmap = (unsigned*)w; w += (size_t)HB*4;
    int* rep  = (int*)w; w += (size_t)NSLOT*4;
    int* cnt  = (int*)w; w += (size_t)NSEG*4;
    int* csr  = (int*)w; w += (size_t)NSEG*SEGCAP*4;
    float* aggOut = (float*)w; w += (size_t)NSEG*DIM*4;
    float* xWr = (float*)w; w += (size_t)NSLOT*DIM*4;

    k_prep      <<<13, 256, 0, stream>>>(Wp, Wc, Wl, Wr, aspv, adpv, ascv, adcv,
                                         s, bm, hmap, rep, cnt, wa, WT4);
    k_castbuild <<<NCAST+NBUILD, 256, 0, stream>>>(X, wa, Xbf, asp, adp, asc, adc,
                                                   EI, bm, hmap, cnt, csr);
    k_aggemm    <<<NAGG+16, 256, 0, stream>>>(Xbf, asp, adp, asc, adc, s, cnt, csr,
                                              WT4, aggOut, xWr);
    k_gather    <<<NT*NSLOT*DIM/256, 256, 0, stream>>>(rep, aggOut, xWr, bp, bc, bl, br, out);
}

// Round 16
// 73.946 us; speedup vs baseline: 13.8197x; 1.0469x over previous
//
#include <hip/hip_runtime.h>
#include <hip/hip_bf16.h>

#define NN 30000
#define DIM 128
#define NT 6
#define NE 480000
#define NSLOT 1024
#define NSEG (NT*3*NSLOT)   // 18432
#define SEGCAP 96
#define NBM ((NN+31)/32)    // 938
#define QCAP 2048
#define HB 2048
#define NBUILD 2124         // 118*18
#define NCAST 876
#define NAGG (NSEG/16)      // 1152

typedef __attribute__((ext_vector_type(8))) short bf16x8;
typedef __attribute__((ext_vector_type(4))) float f32x4;

__device__ __forceinline__ float lrelu(float x){ return x > 0.f ? x : 0.2f*x; }
__device__ __forceinline__ unsigned short f2b(float f){
    unsigned u = __float_as_uint(f);
    u = (u + 0x7FFFu + ((u>>16)&1u)) >> 16;
    return (unsigned short)u;
}
__device__ __forceinline__ float b2f(unsigned short b){
    return __uint_as_float(((unsigned)b)<<16);
}
__device__ __forceinline__ float blo(unsigned p){ return b2f((unsigned short)(p & 0xFFFF)); }
__device__ __forceinline__ float bhi(unsigned p){ return b2f((unsigned short)(p >> 16)); }
__device__ __forceinline__ unsigned hsh(int v){ return ((unsigned)v*2654435761u >> 21) & (HB-1); }

// blocks 0..3: WT transpose (+wa for 0,1); block 4: hash/bitmap/rep; blocks 5..12: zero cnt
__global__ void k_prep(const float* __restrict__ Wp, const float* __restrict__ Wc,
        const float* __restrict__ Wl, const float* __restrict__ Wr,
        const float* __restrict__ aspv, const float* __restrict__ adpv,
        const float* __restrict__ ascv, const float* __restrict__ adcv,
        const int* __restrict__ s, unsigned* __restrict__ bm,
        unsigned* __restrict__ hmap, int* __restrict__ rep, int* __restrict__ cnt,
        float* __restrict__ wa, unsigned short* __restrict__ WT4){
    int m = blockIdx.x, t = threadIdx.x;
    if (m >= 5){
        int b = m - 5;
        int per = (NSEG + 7)/8;
        for (int j = b*per + t; j < (b+1)*per && j < NSEG; j += 256) cnt[j] = 0;
        return;
    }
    if (m == 4){
        __shared__ int hk[HB];
        __shared__ int hv[HB];
        __shared__ unsigned bms[NBM];
        for (int j = t; j < HB; j += 256){ hk[j] = -1; hv[j] = 1<<30; }
        for (int j = t; j < NBM; j += 256) bms[j] = 0u;
        __syncthreads();
        for (int i = t; i < NSLOT; i += 256){
            int v = s[i];
            unsigned idx = hsh(v);
            while (true){
                int old = atomicCAS(&hk[idx], -1, v);
                if (old == -1 || old == v){ atomicMin(&hv[idx], i); break; }
                idx = (idx+1)&(HB-1);
            }
            atomicOr(&bms[v>>5], 1u << (v&31));
        }
        __syncthreads();
        for (int j = t; j < NBM; j += 256) bm[j] = bms[j];
        for (int j = t; j < HB; j += 256){
            int k = hk[j];
            hmap[j] = (k < 0) ? 0xFFFFFFFFu : (((unsigned)k << 10) | (unsigned)hv[j]);
        }
        for (int i = t; i < NSLOT; i += 256){
            int v = s[i];
            unsigned idx = hsh(v);
            while (hk[idx] != v) idx = (idx+1)&(HB-1);
            rep[i] = hv[idx];
        }
        return;
    }
    const float* W = (m==0) ? Wp : (m==1) ? Wc : (m==2) ? Wl : Wr;
    unsigned short* WT = WT4 + (size_t)m*DIM*DIM;
    if (m < 2 && t < DIM){
        const float* avs = m ? ascv : aspv;
        const float* avd = m ? adcv : adpv;
        float* wab = wa + m*2*DIM;
        float sv = 0.f, dv = 0.f;
        for (int n = 0; n < DIM; n++){
            float w = W[t*DIM + n];
            sv += w*avs[n]; dv += w*avd[n];
        }
        wab[t] = sv; wab[DIM + t] = dv;
    }
    for (int j = t; j < DIM*DIM; j += blockDim.x){
        int n = j >> 7, k = j & 127;
        WT[n*DIM + k] = f2b(W[k*DIM + n]);
    }
}

// blocks [0,NCAST): cast (grid-stride, wave/node); [NCAST, NCAST+NBUILD): CSR build
__global__ __launch_bounds__(256) void k_castbuild(
        const float* __restrict__ X, const float* __restrict__ wa,
        unsigned* __restrict__ Xbf,
        float* __restrict__ asp, float* __restrict__ adp,
        float* __restrict__ asc, float* __restrict__ adc,
        const int* __restrict__ EI,
        const unsigned* __restrict__ bm, const unsigned* __restrict__ hmap,
        int* __restrict__ cnt, int* __restrict__ csr){
    __shared__ unsigned bms[NBM];
    __shared__ unsigned q[QCAP];
    __shared__ int qn;
    int bx = blockIdx.x;
    int lane = threadIdx.x & 63;
    int wib = threadIdx.x >> 6;
    if (bx < NCAST){
        for (int node = bx*4 + wib; node < NN; node += NCAST*4){
            float2 x = *(const float2*)&X[(size_t)node*DIM + lane*2];
            Xbf[(size_t)node*64 + lane] = (unsigned)f2b(x.x) | ((unsigned)f2b(x.y) << 16);
            float sp = x.x*wa[2*lane]     + x.y*wa[2*lane+1];
            float dp = x.x*wa[128+2*lane] + x.y*wa[128+2*lane+1];
            float sc = x.x*wa[256+2*lane] + x.y*wa[256+2*lane+1];
            float dc = x.x*wa[384+2*lane] + x.y*wa[384+2*lane+1];
            #pragma unroll
            for (int off = 32; off; off >>= 1){
                sp += __shfl_xor(sp, off); dp += __shfl_xor(dp, off);
                sc += __shfl_xor(sc, off); dc += __shfl_xor(dc, off);
            }
            if (lane == 0){ asp[node]=sp; adp[node]=dp; asc[node]=sc; adc[node]=dc; }
        }
        return;
    }
    int bb = bx - NCAST;
    int row = bb / 118, bxx = bb - row*118;
    for (int j = threadIdx.x; j < NBM; j += 256) bms[j] = bm[j];
    if (threadIdx.x == 0) qn = 0;
    __syncthreads();
    const int Q = NE/4;
    const int G = 118*256;
    const int4* dstp = (const int4*)(EI + (size_t)(2*row+1)*NE);
    const int4* srcp = (const int4*)(EI + (size_t)(2*row)*NE);
    int tid = bxx*256 + threadIdx.x;

    int4 d[4]; int ix[4]; bool va[4];
    #pragma unroll
    for (int u = 0; u < 4; u++){
        ix[u] = tid + u*G;
        va[u] = ix[u] < Q;
        d[u] = va[u] ? dstp[ix[u]] : make_int4(0,0,0,0);
    }
    unsigned mk[4];
    #pragma unroll
    for (int u = 0; u < 4; u++){
        unsigned m0 = va[u] ? ((bms[d[u].x>>5] >> (d[u].x&31)) & 1u) : 0u;
        unsigned m1 = va[u] ? ((bms[d[u].y>>5] >> (d[u].y&31)) & 1u) : 0u;
        unsigned m2 = va[u] ? ((bms[d[u].z>>5] >> (d[u].z&31)) & 1u) : 0u;
        unsigned m3 = va[u] ? ((bms[d[u].w>>5] >> (d[u].w&31)) & 1u) : 0u;
        mk[u] = m0 | (m1<<1) | (m2<<2) | (m3<<3);
    }
    int4 sv[4];
    #pragma unroll
    for (int u = 0; u < 4; u++)
        if (mk[u]) sv[u] = srcp[ix[u]];
    #pragma unroll
    for (int u = 0; u < 4; u++){
        #pragma unroll
        for (int c = 0; c < 4; c++){
            bool p = (mk[u] >> c) & 1u;
            unsigned long long bal = __ballot(p);
            if (bal){
                int cntw = __popcll(bal);
                int base = 0;
                if (lane == 0) base = atomicAdd(&qn, cntw);
                base = __shfl(base, 0);
                if (p){
                    int dv = (c==0)?d[u].x:(c==1)?d[u].y:(c==2)?d[u].z:d[u].w;
                    int so = (c==0)?sv[u].x:(c==1)?sv[u].y:(c==2)?sv[u].z:sv[u].w;
                    int pos = base + __popcll(bal & ((1ull<<lane)-1ull));
                    if (pos < QCAP) q[pos] = ((unsigned)dv<<15) | (unsigned)so;
                }
            }
        }
    }
    __syncthreads();
    int base = row*NSLOT;
    int tot = qn; if (tot > QCAP) tot = QCAP;
    for (int j = threadIdx.x; j < tot; j += 256){
        unsigned e = q[j];
        int dst = (int)(e >> 15);
        int src = (int)(e & 32767u);
        unsigned idx = hsh(dst);
        unsigned he;
        while (((he = hmap[idx]) >> 10) != (unsigned)dst) idx = (idx+1)&(HB-1);
        int sl = (int)(he & 1023u);
        int p = atomicAdd(&cnt[base+sl], 1);
        if (p < SEGCAP) csr[(size_t)(base+sl)*SEGCAP + p] = src;
    }
}

// blocks [0,NAGG): 16 segments/block -> aggregate to LDS -> 16x128x128 MFMA -> aggOut
// blocks [NAGG, NAGG+16): Xbf[s]@WrT -> xWr
__global__ __launch_bounds__(256) void k_aggemm(const unsigned* __restrict__ Xbf,
        const float* __restrict__ asp, const float* __restrict__ adp,
        const float* __restrict__ asc, const float* __restrict__ adc,
        const int* __restrict__ s, const int* __restrict__ cnt, const int* __restrict__ csr,
        const unsigned short* __restrict__ WT4,
        float* __restrict__ aggOut, float* __restrict__ xWr){
    __shared__ unsigned tile[16][72];   // 288B row: 16B-aligned, low-conflict
    int bx = blockIdx.x;
    int lane = threadIdx.x & 63;
    int wib = threadIdx.x >> 6;
    if (bx >= NAGG){
        int blk = bx - NAGG;
        const unsigned short* WT = WT4 + (size_t)3*DIM*DIM;
        int r0 = blk*64 + wib*16;
        int ar = r0 + (lane & 15); if (ar > NSLOT-1) ar = NSLOT-1;
        int g4 = lane >> 4;
        const unsigned short* Arow = (const unsigned short*)(Xbf + (size_t)s[ar]*64);
        bf16x8 Af[4];
        #pragma unroll
        for (int ks = 0; ks < 4; ks++)
            Af[ks] = *(const bf16x8*)&Arow[ks*32 + g4*8];
        int cl = lane & 15;
        #pragma unroll
        for (int ct = 0; ct < 8; ct++){
            f32x4 acc = {0.f,0.f,0.f,0.f};
            int bcol = ct*16 + cl;
            #pragma unroll
            for (int ks = 0; ks < 4; ks++){
                bf16x8 bF = *(const bf16x8*)&WT[bcol*DIM + ks*32 + g4*8];
                acc = __builtin_amdgcn_mfma_f32_16x16x32_bf16(Af[ks], bF, acc, 0, 0, 0);
            }
            #pragma unroll
            for (int r = 0; r < 4; r++){
                int rw = r0 + g4*4 + r;
                if (rw < NSLOT) xWr[(size_t)rw*DIM + bcol] = acc[r];
            }
        }
        return;
    }
    int base_gw = bx*16;
    int tg = base_gw >> 10;
    int g = tg % 3;
    const float* as = (g==1) ? asc : asp;
    const float* ad = (g==1) ? adc : adp;

    // ---- hoisted segment heads: all loads issued independently ----
    int nA[4], s0A[4], s1A[4];
    #pragma unroll
    for (int k = 0; k < 4; k++)
        nA[k] = cnt[base_gw + wib*4 + k];
    #pragma unroll
    for (int k = 0; k < 4; k++){
        const int* lst = csr + (size_t)(base_gw + wib*4 + k)*SEGCAP;
        s0A[k] = lst[lane];
        s1A[k] = (lane < 32) ? lst[64+lane] : 0;   // entries >=96 never used
    }
    #pragma unroll
    for (int k = 0; k < 4; k++){
        if (nA[k] > SEGCAP) nA[k] = SEGCAP;
        if (lane >= nA[k]) s0A[k] = 0;
        if (64+lane >= nA[k]) s1A[k] = 0;
    }
    float w0A[4], w1A[4], wsA[4], scA[4];
    unsigned pkvA[4];
    int vA[4];
    if (g < 2){
        #pragma unroll
        for (int k = 0; k < 4; k++)
            vA[k] = s[(base_gw + wib*4 + k) & (NSLOT-1)];
        float advA[4], easA[4];
        #pragma unroll
        for (int k = 0; k < 4; k++){ advA[k] = ad[vA[k]]; easA[k] = as[vA[k]]; }
        float e0A[4], e1A[4];
        #pragma unroll
        for (int k = 0; k < 4; k++){
            e0A[k] = as[s0A[k]];
            e1A[k] = as[s1A[k]];
        }
        #pragma unroll
        for (int k = 0; k < 4; k++)
            pkvA[k] = Xbf[(size_t)vA[k]*64 + lane];
        #pragma unroll
        for (int k = 0; k < 4; k++){
            float eself = lrelu(easA[k] + advA[k]);
            float e0 = (lane < nA[k])    ? lrelu(e0A[k] + advA[k]) : -3e38f;
            float e1 = (64+lane < nA[k]) ? lrelu(e1A[k] + advA[k]) : -3e38f;
            float m = fmaxf(eself, fmaxf(e0, e1));
            #pragma unroll
            for (int off = 32; off; off >>= 1) m = fmaxf(m, __shfl_xor(m, off));
            float w0 = (lane < nA[k])    ? __expf(e0 - m) : 0.f;
            float w1 = (64+lane < nA[k]) ? __expf(e1 - m) : 0.f;
            float ds = w0 + w1;
            #pragma unroll
            for (int off = 32; off; off >>= 1) ds += __shfl_xor(ds, off);
            float wself = __expf(eself - m);
            w0A[k] = w0; w1A[k] = w1; wsA[k] = wself;
            scA[k] = 1.f / (wself + ds);
        }
    } else {
        #pragma unroll
        for (int k = 0; k < 4; k++){
            w0A[k] = (lane < nA[k]) ? 1.f : 0.f;
            w1A[k] = (64+lane < nA[k]) ? 1.f : 0.f;
            wsA[k] = 0.f;
            scA[k] = 1.f / (float)(nA[k] > 0 ? nA[k] : 1);
        }
    }

    // ---- gather-accumulate per segment ----
    #pragma unroll
    for (int k = 0; k < 4; k++){
        int n = nA[k];
        int n0 = n < 64 ? n : 64;
        int src0 = s0A[k], src1 = s1A[k];
        float w0 = w0A[k], w1 = w1A[k];
        float a0 = 0.f, a1 = 0.f;
        int j = 0;
        for (; j+7 < n0; j += 8){
            int   si[8]; float qi[8]; unsigned ki[8];
            #pragma unroll
            for (int u = 0; u < 8; u++){ si[u] = __shfl(src0, j+u); qi[u] = __shfl(w0, j+u); }
            #pragma unroll
            for (int u = 0; u < 8; u++) ki[u] = Xbf[(size_t)si[u]*64 + lane];
            #pragma unroll
            for (int u = 0; u < 8; u++){ a0 += qi[u]*blo(ki[u]); a1 += qi[u]*bhi(ki[u]); }
        }
        for (; j+3 < n0; j += 4){
            int s0=__shfl(src0,j), s1=__shfl(src0,j+1), s2=__shfl(src0,j+2), s3=__shfl(src0,j+3);
            float q0=__shfl(w0,j), q1=__shfl(w0,j+1), q2=__shfl(w0,j+2), q3=__shfl(w0,j+3);
            unsigned k0=Xbf[(size_t)s0*64+lane];
            unsigned k1=Xbf[(size_t)s1*64+lane];
            unsigned k2=Xbf[(size_t)s2*64+lane];
            unsigned k3=Xbf[(size_t)s3*64+lane];
            a0 += q0*blo(k0) + q1*blo(k1) + q2*blo(k2) + q3*blo(k3);
            a1 += q0*bhi(k0) + q1*bhi(k1) + q2*bhi(k2) + q3*bhi(k3);
        }
        for (; j < n0; j++){
            int sj=__shfl(src0,j);
            float qj=__shfl(w0,j);
            unsigned pk=Xbf[(size_t)sj*64+lane];
            a0 += qj*blo(pk); a1 += qj*bhi(pk);
        }
        for (j = 64; j < n; j++){
            int sj=__shfl(src1,j-64);
            float qj=__shfl(w1,j-64);
            unsigned pk=Xbf[(size_t)sj*64+lane];
            a0 += qj*blo(pk); a1 += qj*bhi(pk);
        }
        if (g < 2){
            a0 += wsA[k]*blo(pkvA[k]);
            a1 += wsA[k]*bhi(pkvA[k]);
        }
        tile[wib*4+k][lane] = (unsigned)f2b(a0*scA[k]) | ((unsigned)f2b(a1*scA[k]) << 16);
    }
    __syncthreads();
    // GEMM: 16 rows x 128 cols, wave wib does cols [wib*32, wib*32+32)
    const unsigned short* WT = WT4 + (size_t)g*DIM*DIM;
    int r = lane & 15, g4 = lane >> 4;
    bf16x8 Af[4];
    #pragma unroll
    for (int ks = 0; ks < 4; ks++)
        Af[ks] = *(const bf16x8*)&tile[r][ks*16 + g4*4];
    #pragma unroll
    for (int ct = 0; ct < 2; ct++){
        f32x4 acc = {0.f,0.f,0.f,0.f};
        int bcol = wib*32 + ct*16 + r;
        #pragma unroll
        for (int ks = 0; ks < 4; ks++){
            bf16x8 bF = *(const bf16x8*)&WT[bcol*DIM + ks*32 + g4*8];
            acc = __builtin_amdgcn_mfma_f32_16x16x32_bf16(Af[ks], bF, acc, 0, 0, 0);
        }
        #pragma unroll
        for (int rr = 0; rr < 4; rr++){
            int segrow = g4*4 + rr;
            aggOut[(size_t)(base_gw + segrow)*DIM + bcol] = acc[rr];
        }
    }
}

__global__ void k_gather(const int* __restrict__ rep,
                         const float* __restrict__ aggOut, const float* __restrict__ xWr,
                         const float* __restrict__ bp, const float* __restrict__ bc,
                         const float* __restrict__ bl, const float* __restrict__ br,
                         float* __restrict__ out){
    int i = blockIdx.x*blockDim.x + threadIdx.x;
    if (i >= NT*NSLOT*DIM) return;
    int d = i & 127;
    int r = (i >> 7) & (NSLOT-1);
    int t = i >> 17;
    int rp = rep[r];
    size_t base = ((size_t)(t*3)*NSLOT + rp)*DIM + d;
    out[i] = (aggOut[base] + aggOut[base + NSLOT*DIM] + aggOut[base + 2*NSLOT*DIM]
              + xWr[(size_t)rp*DIM + d]
              + bp[d] + bc[d] + bl[d] + br[d]) * (1.f/3.f);
}

extern "C" void kernel_launch(void* const* d_in, const int* in_sizes, int n_in,
                              void* d_out, int out_size, void* d_ws, size_t ws_size,
                              hipStream_t stream) {
    const int*   s    = (const int*)d_in[0];
    const int*   EI   = (const int*)d_in[3];
    const float* X    = (const float*)d_in[4];
    const float* Wp   = (const float*)d_in[5];
    const float* aspv = (const float*)d_in[6];
    const float* adpv = (const float*)d_in[7];
    const float* bp   = (const float*)d_in[8];
    const float* Wc   = (const float*)d_in[9];
    const float* ascv = (const float*)d_in[10];
    const float* adcv = (const float*)d_in[11];
    const float* bc   = (const float*)d_in[12];
    const float* Wl   = (const float*)d_in[13];
    const float* bl   = (const float*)d_in[14];
    const float* Wr   = (const float*)d_in[15];
    const float* br   = (const float*)d_in[16];
    float* out = (float*)d_out;

    char* w = (char*)d_ws;
    unsigned* Xbf = (unsigned*)w; w += (size_t)NN*64*4;
    unsigned short* WT4 = (unsigned short*)w; w += (size_t)4*DIM*DIM*2;
    float* wa  = (float*)w; w += (size_t)4*DIM*4;
    float* asp = (float*)w; w += (size_t)NN*4;
    float* adp = (float*)w; w += (size_t)NN*4;
    float* asc = (float*)w; w += (size_t)NN*4;
    float* adc = (float*)w; w += (size_t)NN*4;
    unsigned* bm = (unsigned*)w; w += (size_t)((NBM+3)&~3)*4;
    unsigned* hmap = (unsigned*)w; w += (size_t)HB*4;
    int* rep  = (int*)w; w += (size_t)NSLOT*4;
    int* cnt  = (int*)w; w += (size_t)NSEG*4;
    int* csr  = (int*)w; w += (size_t)NSEG*SEGCAP*4;
    float* aggOut = (float*)w; w += (size_t)NSEG*DIM*4;
    float* xWr = (float*)w; w += (size_t)NSLOT*DIM*4;

    k_prep      <<<13, 256, 0, stream>>>(Wp, Wc, Wl, Wr, aspv, adpv, ascv, adcv,
                                         s, bm, hmap, rep, cnt, wa, WT4);
    k_castbuild <<<NCAST+NBUILD, 256, 0, stream>>>(X, wa, Xbf, asp, adp, asc, adc,
                                                   EI, bm, hmap, cnt, csr);
    k_aggemm    <<<NAGG+16, 256, 0, stream>>>(Xbf, asp, adp, asc, adc, s, cnt, csr,
                                              WT4, aggOut, xWr);
    k_gather    <<<NT*NSLOT*DIM/256, 256, 0, stream>>>(rep, aggOut, xWr, bp, bc, bl, br, out);
}